// Round 4
// baseline (443.712 us; speedup 1.0000x reference)
//
#include <hip/hip_runtime.h>

typedef __attribute__((ext_vector_type(8))) short short8;
typedef __attribute__((ext_vector_type(4))) float f32x4;
typedef unsigned short ushort_t;
typedef unsigned int uint_t;

#define VOCAB 401
#define T_ 140
#define E_ 128
#define H_ 256
#define B_ 4096
#define HPAD 264  // shorts per hB row: 528 B -> 16B-aligned, col-stride 132 dw == 4 mod 32 banks (conflict-free b128)

// Device-global scratch (no d_ws dependence). Rewritten fully every launch.
__device__ float Gf[VOCAB * 768];       // gi gather table (b_ih + b_hh folded for r,z)
__device__ ushort_t WhhB[768 * H_];     // canonical bf16 W_hh

__device__ __forceinline__ float bf2f(ushort_t u) {
  union { uint_t i; float f; } x; x.i = ((uint_t)u) << 16; return x.f;
}
__device__ __forceinline__ ushort_t f2bf(float f) {
  union { float f; uint_t i; } x; x.f = f;
  uint_t r = x.i + 0x7FFFu + ((x.i >> 16) & 1u);
  return (ushort_t)(r >> 16);
}
__device__ __forceinline__ float fast_sigmoid(float x) {
  return __builtin_amdgcn_rcpf(1.f + __builtin_amdgcn_exp2f(-1.442695041f * x));
}
__device__ __forceinline__ float fast_tanh(float x) {
  return 1.f - 2.f * __builtin_amdgcn_rcpf(1.f + __builtin_amdgcn_exp2f(2.885390082f * x));
}
__device__ __forceinline__ float ldf(const void* p, size_t i, int isb) {
  return isb ? bf2f(((const ushort_t*)p)[i]) : ((const float*)p)[i];
}
__device__ __forceinline__ void ld8f(const void* p, size_t idx, int isb, float* o) {
  if (isb) {
    short8 v = *(const short8*)((const ushort_t*)p + idx);
#pragma unroll
    for (int e = 0; e < 8; ++e) o[e] = bf2f((ushort_t)v[e]);
  } else {
    f32x4 a = *(const f32x4*)((const float*)p + idx);
    f32x4 b = *(const f32x4*)((const float*)p + idx + 4);
#pragma unroll
    for (int e = 0; e < 4; ++e) { o[e] = a[e]; o[4 + e] = b[e]; }
  }
}
// In-block dtype probe (wave 0): bf16 N(0,1) -> sane exponent ~64/64; f32
// low-mantissa shorts -> ~10/64. Threshold 40.
__device__ __forceinline__ int block_probe_isbf16(const ushort_t* embed_raw, int* s) {
  if (threadIdx.x < 64) {
    ushort_t v = embed_raw[2 * threadIdx.x];
    int e = (v >> 7) & 0xFF;
    unsigned long long m = __ballot(e >= 100 && e <= 140);
    if (threadIdx.x == 0) *s = (__popcll(m) >= 40) ? 1 : 0;
  }
  __syncthreads();
  return *s;
}

// ---------------------------------------------------------------------------
// Canonicalize W_hh to bf16.
// ---------------------------------------------------------------------------
__global__ void canon_whh(const void* __restrict__ W_hh, const ushort_t* __restrict__ embed_raw) {
  __shared__ int sISB;
  int isb = block_probe_isbf16(embed_raw, &sISB);
  int i4 = (blockIdx.x * 256 + threadIdx.x) * 4;  // grid 192 covers 768*256
  if (isb) {
    *(uint2*)&WhhB[i4] = *(const uint2*)((const ushort_t*)W_hh + i4);
  } else {
    f32x4 v = *(const f32x4*)((const float*)W_hh + i4);
    uint2 pk;
    pk.x = (uint_t)f2bf(v[0]) | ((uint_t)f2bf(v[1]) << 16);
    pk.y = (uint_t)f2bf(v[2]) | ((uint_t)f2bf(v[3]) << 16);
    *(uint2*)&WhhB[i4] = pk;
  }
}

// ---------------------------------------------------------------------------
// G[v][row] = dot(embed[v], W_ih[row]) + b_ih[row] + (row<512 ? b_hh[row] : 0)
// 8 vocab ids per block: W_ih read once per 8 v's (79 MB -> 10 MB traffic).
// ---------------------------------------------------------------------------
__global__ void build_G(const void* __restrict__ embed,
                        const void* __restrict__ W_ih,
                        const void* __restrict__ b_ih,
                        const void* __restrict__ b_hh) {
  __shared__ float emb[8][E_];
  __shared__ int sISB;
  const int isb = block_probe_isbf16((const ushort_t*)embed, &sISB);
  const int vb = blockIdx.x;   // 0..50
  const int g  = blockIdx.y;   // 0..2
  const int j  = threadIdx.x;  // 0..255
  for (int idx = j; idx < 8 * E_; idx += 256) {
    int s = idx >> 7, e = idx & 127;
    int v = vb * 8 + s; if (v > VOCAB - 1) v = VOCAB - 1;
    emb[s][e] = ldf(embed, (size_t)v * E_ + e, isb);
  }
  __syncthreads();
  const int row = g * H_ + j;
  float acc[8];
#pragma unroll
  for (int s = 0; s < 8; ++s) acc[s] = 0.f;
  for (int k8 = 0; k8 < E_ / 8; ++k8) {
    float wv[8];
    ld8f(W_ih, (size_t)row * E_ + k8 * 8, isb, wv);
#pragma unroll
    for (int s = 0; s < 8; ++s)
#pragma unroll
      for (int e = 0; e < 8; ++e) acc[s] += emb[s][k8 * 8 + e] * wv[e];
  }
  float bias = ldf(b_ih, row, isb) + ((g < 2) ? ldf(b_hh, row, isb) : 0.f);
#pragma unroll
  for (int s = 0; s < 8; ++s) {
    int v = vb * 8 + s;
    if (v < VOCAB) Gf[v * 768 + row] = acc[s] + bias;
  }
}

// ---------------------------------------------------------------------------
// Persistent GRU. 256 WGs x 512 threads (8 waves); WG owns 16 batch rows.
// Each wave owns 32 units (2 M-tiles) x 3 gates: 48 A-frags = 192 regs (AGPR).
// Split-phase per step: MFMA-t0 -> math-t0 -> MFMA-t1 -> math-t1 -> barrier,
// so one wave's MFMA overlaps the other wave's gate-VALU on each SIMD.
// b_hh_n folded into n-gate MFMA C-init; G(t+1) prefetched into dead acc regs.
// ---------------------------------------------------------------------------
__launch_bounds__(512, 2)
__global__ void gru_persist(const int* __restrict__ input,
                            const void* __restrict__ hidden,
                            const void* __restrict__ b_hh,
                            const void* __restrict__ W_out,
                            const void* __restrict__ b_out,
                            const ushort_t* __restrict__ embed_raw,
                            void* __restrict__ out) {
  __shared__ ushort_t hB[2][16 * HPAD];
  __shared__ float bhhn[H_];
  __shared__ int ids[16 * (T_ + 1)];
  __shared__ int sISB;

  const int isb  = block_probe_isbf16(embed_raw, &sISB);
  const int tid  = threadIdx.x;
  const int w    = tid >> 6;        // wave 0..7
  const int lane = tid & 63;
  const int quad = lane >> 4;
  const int col  = lane & 15;       // batch column
  const int wg   = blockIdx.x;
  const int u0   = w << 5;                  // 32 units/wave
  const int u0q0 = u0 + (quad << 2);        // tile0 C-rows
  const int u0q1 = u0 + 16 + (quad << 2);   // tile1 C-rows

  // ---- stage h0 (512 threads cover 16x256) ----
  {
    int r = tid >> 5, c0 = (tid & 31) << 3;
    size_t gi = (size_t)(wg * 16 + r) * H_ + c0;
    ushort_t* dst = &hB[0][r * HPAD + c0];
    if (isb) {
      *(short8*)dst = *(const short8*)((const ushort_t*)hidden + gi);
    } else {
      float tmp[8];
      ld8f(hidden, gi, 0, tmp);
#pragma unroll
      for (int e = 0; e < 8; ++e) dst[e] = f2bf(tmp[e]);
    }
  }
  if (tid < H_) bhhn[tid] = ldf(b_hh, 512 + tid, isb);
  // ids as pre-scaled byte offsets; stride T_+1, entry [*,T_] = 0 (pad for prefetch)
  for (int k = tid; k < 16 * (T_ + 1); k += 512) {
    int b = k / (T_ + 1), t = k - b * (T_ + 1);
    ids[k] = (t < T_) ? input[(size_t)wg * 16 * T_ + b * T_ + t] * 3072 : 0;
  }

  // ---- persistent W_hh fragments: A[m=lane&15][k=quad*8+j] ----
  short8 wA[3][2][8];
#pragma unroll
  for (int g = 0; g < 3; ++g)
#pragma unroll
    for (int tl = 0; tl < 2; ++tl) {
      const ushort_t* wrow = WhhB + (size_t)(g * H_ + u0 + tl * 16 + col) * H_ + (quad << 3);
#pragma unroll
      for (int kt = 0; kt < 8; ++kt) wA[g][tl][kt] = *(const short8*)(wrow + kt * 32);
    }

  __syncthreads();

  float hreg0[4], hreg1[4];
#pragma unroll
  for (int i = 0; i < 4; ++i) {
    hreg0[i] = bf2f(hB[0][col * HPAD + u0q0 + i]);
    hreg1[i] = bf2f(hB[0][col * HPAD + u0q1 + i]);
  }
  const f32x4 bh0 = *(const f32x4*)&bhhn[u0q0];
  const f32x4 bh1 = *(const f32x4*)&bhhn[u0q1];

  const int idbase = col * (T_ + 1);
  const char* gB = (const char*)Gf + (size_t)u0q0 * 4;  // tile1 slices at +64 B

  f32x4 a0r, a0z, g0n, a1r, a1z, g1n;
  {
    int goff = ids[idbase];
    a0r = *(const f32x4*)(gB + goff);
    a0z = *(const f32x4*)(gB + goff + 1024);
    g0n = *(const f32x4*)(gB + goff + 2048);
    a1r = *(const f32x4*)(gB + goff + 64);
    a1z = *(const f32x4*)(gB + goff + 1024 + 64);
    g1n = *(const f32x4*)(gB + goff + 2048 + 64);
  }

#pragma unroll 2
  for (int t = 0; t < T_; ++t) {
    const int cur = t & 1;
    const int nxt = cur ^ 1;
    const ushort_t* hr = &hB[cur][col * HPAD + (quad << 3)];
    const int goff_n = ids[idbase + t + 1];

    // ================= tile 0 =================
    f32x4 a0n = bh0;  // b_hh_n folded as C-init
#pragma unroll
    for (int kt = 0; kt < 8; ++kt) {
      short8 b = *(const short8*)(hr + kt * 32);
      a0r = __builtin_amdgcn_mfma_f32_16x16x32_bf16(wA[0][0][kt], b, a0r, 0, 0, 0);
      a0z = __builtin_amdgcn_mfma_f32_16x16x32_bf16(wA[1][0][kt], b, a0z, 0, 0, 0);
      a0n = __builtin_amdgcn_mfma_f32_16x16x32_bf16(wA[2][0][kt], b, a0n, 0, 0, 0);
    }
    {
      uint_t rr[4];
#pragma unroll
      for (int i = 0; i < 4; ++i) {
        float r_ = fast_sigmoid(a0r[i]);
        float z_ = fast_sigmoid(a0z[i]);
        float n  = fast_tanh(g0n[i] + r_ * a0n[i]);
        float h  = n + z_ * (hreg0[i] - n);
        hreg0[i] = h;
        union { float f; uint_t u; } c; c.f = h;
        rr[i] = c.u + 0x7FFFu + ((c.u >> 16) & 1u);
      }
      ushort_t* hw = &hB[nxt][col * HPAD + u0q0];
      *(uint_t*)&hw[0] = __builtin_amdgcn_perm(rr[1], rr[0], 0x07060302);
      *(uint_t*)&hw[2] = __builtin_amdgcn_perm(rr[3], rr[2], 0x07060302);
    }
    // prefetch tile0 G(t+1) into dead acc regs; latency covered by tile1 MFMA
    a0r = *(const f32x4*)(gB + goff_n);
    a0z = *(const f32x4*)(gB + goff_n + 1024);
    g0n = *(const f32x4*)(gB + goff_n + 2048);

    // ================= tile 1 =================
    f32x4 a1n = bh1;
#pragma unroll
    for (int kt = 0; kt < 8; ++kt) {
      short8 b = *(const short8*)(hr + kt * 32);  // re-read: frees 32 VGPRs vs keeping live
      a1r = __builtin_amdgcn_mfma_f32_16x16x32_bf16(wA[0][1][kt], b, a1r, 0, 0, 0);
      a1z = __builtin_amdgcn_mfma_f32_16x16x32_bf16(wA[1][1][kt], b, a1z, 0, 0, 0);
      a1n = __builtin_amdgcn_mfma_f32_16x16x32_bf16(wA[2][1][kt], b, a1n, 0, 0, 0);
    }
    {
      uint_t rr[4];
#pragma unroll
      for (int i = 0; i < 4; ++i) {
        float r_ = fast_sigmoid(a1r[i]);
        float z_ = fast_sigmoid(a1z[i]);
        float n  = fast_tanh(g1n[i] + r_ * a1n[i]);
        float h  = n + z_ * (hreg1[i] - n);
        hreg1[i] = h;
        union { float f; uint_t u; } c; c.f = h;
        rr[i] = c.u + 0x7FFFu + ((c.u >> 16) & 1u);
      }
      ushort_t* hw = &hB[nxt][col * HPAD + u0q1];
      *(uint_t*)&hw[0] = __builtin_amdgcn_perm(rr[1], rr[0], 0x07060302);
      *(uint_t*)&hw[2] = __builtin_amdgcn_perm(rr[3], rr[2], 0x07060302);
    }
    // prefetch tile1 G(t+1); latency covered by barrier + next tile0 MFMA
    a1r = *(const f32x4*)(gB + goff_n + 64);
    a1z = *(const f32x4*)(gB + goff_n + 1024 + 64);
    g1n = *(const f32x4*)(gB + goff_n + 2048 + 64);

    __syncthreads();
  }

  // ---- epilogue: logits + log_softmax; wave w handles local batches w, w+8 ----
  for (int rb = w; rb < 16; rb += 8) {
    const ushort_t* hrow = &hB[0][rb * HPAD + (lane << 2)];
    float h0 = bf2f(hrow[0]), h1 = bf2f(hrow[1]), h2 = bf2f(hrow[2]), h3 = bf2f(hrow[3]);
    float d[3];
#pragma unroll
    for (int o = 0; o < 3; ++o) {
      size_t base = (size_t)o * H_ + (lane << 2);
      d[o] = ldf(W_out, base, isb) * h0 + ldf(W_out, base + 1, isb) * h1 +
             ldf(W_out, base + 2, isb) * h2 + ldf(W_out, base + 3, isb) * h3;
      for (int off = 1; off < 64; off <<= 1) d[o] += __shfl_xor(d[o], off);
    }
    if (lane == 0) {
      float l0 = d[0] + ldf(b_out, 0, isb);
      float l1 = d[1] + ldf(b_out, 1, isb);
      float l2 = d[2] + ldf(b_out, 2, isb);
      float m = fmaxf(l0, fmaxf(l1, l2));
      float s = __builtin_amdgcn_exp2f((l0 - m) * 1.442695041f) +
                __builtin_amdgcn_exp2f((l1 - m) * 1.442695041f) +
                __builtin_amdgcn_exp2f((l2 - m) * 1.442695041f);
      float ls = __builtin_amdgcn_logf(s) * 0.6931471806f;
      size_t ob = (size_t)(wg * 16 + rb) * 3;
      float o0 = l0 - m - ls, o1 = l1 - m - ls, o2 = l2 - m - ls;
      if (isb) {
        ushort_t* ob16 = (ushort_t*)out;
        ob16[ob] = f2bf(o0); ob16[ob + 1] = f2bf(o1); ob16[ob + 2] = f2bf(o2);
      } else {
        float* of = (float*)out;
        of[ob] = o0; of[ob + 1] = o1; of[ob + 2] = o2;
      }
    }
  }
  // ---- h_final copy, coalesced (512 threads x 8 elems) ----
  {
    int e = tid << 3;
    int bb = e >> 8, uu = e & 255;
    const ushort_t* src = &hB[0][bb * HPAD + uu];
    size_t oi = 12288 + (size_t)wg * 4096 + e;
    if (isb) {
      *(short8*)((ushort_t*)out + oi) = *(const short8*)src;
    } else {
      float* of = (float*)out;
#pragma unroll
      for (int q = 0; q < 8; ++q) of[oi + q] = bf2f(src[q]);
    }
  }
}

extern "C" void kernel_launch(void* const* d_in, const int* in_sizes, int n_in,
                              void* d_out, int out_size, void* d_ws, size_t ws_size,
                              hipStream_t stream) {
  (void)in_sizes; (void)n_in; (void)out_size; (void)d_ws; (void)ws_size;
  const int* input = (const int*)d_in[0];
  const void* hidden = d_in[1];
  const void* embed  = d_in[2];
  const void* W_ih   = d_in[3];
  const void* W_hh   = d_in[4];
  const void* b_ih   = d_in[5];
  const void* b_hh   = d_in[6];
  const void* W_out  = d_in[7];
  const void* b_out  = d_in[8];

  canon_whh<<<192, 256, 0, stream>>>(W_hh, (const ushort_t*)embed);
  build_G<<<dim3(51, 3), 256, 0, stream>>>(embed, W_ih, b_ih, b_hh);
  gru_persist<<<B_ / 16, 512, 0, stream>>>(input, hidden, b_hh, W_out, b_out,
                                           (const ushort_t*)embed, d_out);
}

// Round 5
// 363.647 us; speedup vs baseline: 1.2202x; 1.2202x over previous
//
#include <hip/hip_runtime.h>

typedef __attribute__((ext_vector_type(8))) short short8;
typedef __attribute__((ext_vector_type(4))) float f32x4;
typedef unsigned short ushort_t;
typedef unsigned int uint_t;

#define VOCAB 401
#define T_ 140
#define E_ 128
#define H_ 256
#define B_ 4096
#define HPAD 264  // shorts per hB row: 16B-aligned rows

// Device-global scratch (no d_ws dependence). Rewritten fully every launch.
__device__ float Gf[VOCAB * 768];       // gi gather table (b_ih + b_hh folded for r,z)
__device__ ushort_t WhhB[768 * H_];     // canonical bf16 W_hh

__device__ __forceinline__ float bf2f(ushort_t u) {
  union { uint_t i; float f; } x; x.i = ((uint_t)u) << 16; return x.f;
}
__device__ __forceinline__ ushort_t f2bf(float f) {
  union { float f; uint_t i; } x; x.f = f;
  uint_t r = x.i + 0x7FFFu + ((x.i >> 16) & 1u);
  return (ushort_t)(r >> 16);
}
// Saturate correctly through +-inf; no clamps needed.
__device__ __forceinline__ float fast_sigmoid(float x) {
  return __builtin_amdgcn_rcpf(1.f + __builtin_amdgcn_exp2f(-1.442695041f * x));
}
__device__ __forceinline__ float fast_tanh(float x) {
  return 1.f - 2.f * __builtin_amdgcn_rcpf(1.f + __builtin_amdgcn_exp2f(2.885390082f * x));
}
__device__ __forceinline__ float ldf(const void* p, size_t i, int isb) {
  return isb ? bf2f(((const ushort_t*)p)[i]) : ((const float*)p)[i];
}
__device__ __forceinline__ void ld8f(const void* p, size_t idx, int isb, float* o) {
  if (isb) {
    short8 v = *(const short8*)((const ushort_t*)p + idx);
#pragma unroll
    for (int e = 0; e < 8; ++e) o[e] = bf2f((ushort_t)v[e]);
  } else {
    f32x4 a = *(const f32x4*)((const float*)p + idx);
    f32x4 b = *(const f32x4*)((const float*)p + idx + 4);
#pragma unroll
    for (int e = 0; e < 4; ++e) { o[e] = a[e]; o[4 + e] = b[e]; }
  }
}
// In-block dtype probe (wave 0): bf16 N(0,1) -> sane exponent ~64/64; f32
// low-mantissa shorts -> ~10/64. Threshold 40.
__device__ __forceinline__ int block_probe_isbf16(const ushort_t* embed_raw, int* s) {
  if (threadIdx.x < 64) {
    ushort_t v = embed_raw[2 * threadIdx.x];
    int e = (v >> 7) & 0xFF;
    unsigned long long m = __ballot(e >= 100 && e <= 140);
    if (threadIdx.x == 0) *s = (__popcll(m) >= 40) ? 1 : 0;
  }
  __syncthreads();
  return *s;
}

// ---------------------------------------------------------------------------
// Fused prep: blocks 0..152 build G (vb = bid/3, gate = bid%3, 8 vocab/block);
// blocks 153..344 canonicalize W_hh to bf16. One launch instead of two.
// ---------------------------------------------------------------------------
__global__ void prep(const void* __restrict__ W_hh,
                     const void* __restrict__ embed,
                     const void* __restrict__ W_ih,
                     const void* __restrict__ b_ih,
                     const void* __restrict__ b_hh) {
  __shared__ float emb[8][E_];
  __shared__ int sISB;
  const int isb = block_probe_isbf16((const ushort_t*)embed, &sISB);
  const int bid = blockIdx.x;
  const int j = threadIdx.x;  // 0..255

  if (bid >= 153) {
    // ---- canon W_hh ----
    int i4 = ((bid - 153) * 256 + j) * 4;  // 192 blocks cover 768*256
    if (isb) {
      *(uint2*)&WhhB[i4] = *(const uint2*)((const ushort_t*)W_hh + i4);
    } else {
      f32x4 v = *(const f32x4*)((const float*)W_hh + i4);
      uint2 pk;
      pk.x = (uint_t)f2bf(v[0]) | ((uint_t)f2bf(v[1]) << 16);
      pk.y = (uint_t)f2bf(v[2]) | ((uint_t)f2bf(v[3]) << 16);
      *(uint2*)&WhhB[i4] = pk;
    }
    return;
  }

  // ---- build G: G[v][row] = dot(embed[v], W_ih[row]) + b_ih + (gate<2 ? b_hh : 0) ----
  const int vb = bid / 3;
  const int g  = bid - vb * 3;
  for (int idx = j; idx < 8 * E_; idx += 256) {
    int s = idx >> 7, e = idx & 127;
    int v = vb * 8 + s; if (v > VOCAB - 1) v = VOCAB - 1;
    emb[s][e] = ldf(embed, (size_t)v * E_ + e, isb);
  }
  __syncthreads();
  const int row = g * H_ + j;
  float acc[8];
#pragma unroll
  for (int s = 0; s < 8; ++s) acc[s] = 0.f;
  for (int k8 = 0; k8 < E_ / 8; ++k8) {
    float wv[8];
    ld8f(W_ih, (size_t)row * E_ + k8 * 8, isb, wv);
#pragma unroll
    for (int s = 0; s < 8; ++s)
#pragma unroll
      for (int e = 0; e < 8; ++e) acc[s] += emb[s][k8 * 8 + e] * wv[e];
  }
  float bias = ldf(b_ih, row, isb) + ((g < 2) ? ldf(b_hh, row, isb) : 0.f);
#pragma unroll
  for (int s = 0; s < 8; ++s) {
    int v = vb * 8 + s;
    if (v < VOCAB) Gf[v * 768 + row] = acc[s] + bias;
  }
}

// ---------------------------------------------------------------------------
// Persistent GRU. 256 WGs x 1024 threads (16 waves); WG owns 16 batch rows.
// Wave w owns units [16w,16w+16) x 3 gates: 24 A-frags = 96 regs, register-
// resident W_hh. h double-buffered bf16 in LDS + f32 state in regs (C-layout).
// R5: r/z chains first, n-chain interleaved with r/z sigmoids (within-wave
// MFMA/VALU co-issue); b_hh_n folded into n-chain C-init; raw lgkmcnt-only
// barrier keeps the G(t+1) prefetch in flight across the step boundary.
// ---------------------------------------------------------------------------
__launch_bounds__(1024)
__global__ void gru_persist(const int* __restrict__ input,
                            const void* __restrict__ hidden,
                            const void* __restrict__ b_hh,
                            const void* __restrict__ W_out,
                            const void* __restrict__ b_out,
                            const ushort_t* __restrict__ embed_raw,
                            void* __restrict__ out) {
  __shared__ ushort_t hB[2][16 * HPAD];
  __shared__ float bhhn[H_];
  __shared__ int ids[16 * (T_ + 1)];
  __shared__ int sISB;

  const int isb  = block_probe_isbf16(embed_raw, &sISB);
  const int tid  = threadIdx.x;
  const int w    = tid >> 6;
  const int lane = tid & 63;
  const int quad = lane >> 4;
  const int col  = lane & 15;
  const int wg   = blockIdx.x;
  const int u0   = w << 4;
  const int u0q  = u0 + (quad << 2);

  // ---- stage h0 ----
  if (tid < 512) {
    int r = tid >> 5, c0 = (tid & 31) << 3;
    size_t gi = (size_t)(wg * 16 + r) * H_ + c0;
    ushort_t* dst = &hB[0][r * HPAD + c0];
    if (isb) {
      *(short8*)dst = *(const short8*)((const ushort_t*)hidden + gi);
    } else {
      float tmp[8];
      ld8f(hidden, gi, 0, tmp);
#pragma unroll
      for (int e = 0; e < 8; ++e) dst[e] = f2bf(tmp[e]);
    }
  }
  if (tid < H_) bhhn[tid] = ldf(b_hh, 512 + tid, isb);
  // ids as pre-scaled byte offsets; stride T_+1, entry [*,T_] = 0 (prefetch pad)
  for (int k = tid; k < 16 * (T_ + 1); k += 1024) {
    int b = k / (T_ + 1), t = k - b * (T_ + 1);
    ids[k] = (t < T_) ? input[(size_t)wg * 16 * T_ + b * T_ + t] * 3072 : 0;
  }

  // ---- persistent W_hh fragments: A[m=lane&15][k=quad*8+j] ----
  short8 wA[3][8];
#pragma unroll
  for (int g = 0; g < 3; ++g) {
    const ushort_t* wrow = WhhB + (size_t)(g * H_ + u0 + col) * H_ + (quad << 3);
#pragma unroll
    for (int kt = 0; kt < 8; ++kt) wA[g][kt] = *(const short8*)(wrow + kt * 32);
  }

  __syncthreads();

  float hreg[4];
#pragma unroll
  for (int i = 0; i < 4; ++i)
    hreg[i] = bf2f(hB[0][col * HPAD + u0q + i]);

  const int idbase = col * (T_ + 1);
  const char* gB = (const char*)Gf + (size_t)u0q * 4;

  // preload G rows for t=0 directly into acc (C-layout) / gin
  f32x4 accr, accz, gin;
  {
    int goff = ids[idbase];
    accr = *(const f32x4*)(gB + goff);
    accz = *(const f32x4*)(gB + goff + 1024);
    gin  = *(const f32x4*)(gB + goff + 2048);
  }

#pragma unroll 2
  for (int t = 0; t < T_; ++t) {
    const int cur = t & 1;
    const int nxt = cur ^ 1;
    const ushort_t* hr = &hB[cur][col * HPAD + (quad << 3)];
    const int goff_n = ids[idbase + t + 1];
    f32x4 bhv = *(const f32x4*)&bhhn[u0q];  // n-chain C-init (b_hh_n fold)

    // ---- r,z chains: b read once per kt ----
#pragma unroll
    for (int kt = 0; kt < 8; ++kt) {
      short8 b = *(const short8*)(hr + kt * 32);
      accr = __builtin_amdgcn_mfma_f32_16x16x32_bf16(wA[0][kt], b, accr, 0, 0, 0);
      accz = __builtin_amdgcn_mfma_f32_16x16x32_bf16(wA[1][kt], b, accz, 0, 0, 0);
    }
    // ---- n chain, r/z sigmoids interleaved (issue under matrix-pipe time) ----
    f32x4 an = bhv;
    float r_[4], z_[4];
#pragma unroll
    for (int kt = 0; kt < 8; ++kt) {
      short8 b = *(const short8*)(hr + kt * 32);
      an = __builtin_amdgcn_mfma_f32_16x16x32_bf16(wA[2][kt], b, an, 0, 0, 0);
      if (kt < 4) r_[kt] = fast_sigmoid(accr[kt]);
      else        z_[kt - 4] = fast_sigmoid(accz[kt - 4]);
    }

    uint_t rr[4];
#pragma unroll
    for (int i = 0; i < 4; ++i) {
      float n = fast_tanh(gin[i] + r_[i] * an[i]);
      float h = n + z_[i] * (hreg[i] - n);
      hreg[i] = h;
      union { float f; uint_t u; } c; c.f = h;
      rr[i] = c.u + 0x7FFFu + ((c.u >> 16) & 1u);
    }
    ushort_t* hw = &hB[nxt][col * HPAD + u0q];
    *(uint_t*)&hw[0] = __builtin_amdgcn_perm(rr[1], rr[0], 0x07060302);
    *(uint_t*)&hw[2] = __builtin_amdgcn_perm(rr[3], rr[2], 0x07060302);

    // prefetch G rows for t+1 into dead acc regs; raw barrier below keeps
    // these loads in flight (no vmcnt drain) -> latency hidden to next use
    accr = *(const f32x4*)(gB + goff_n);
    accz = *(const f32x4*)(gB + goff_n + 1024);
    gin  = *(const f32x4*)(gB + goff_n + 2048);

    // LDS-only fence + barrier: h writes visible to all waves; vmcnt NOT drained
    asm volatile("s_waitcnt lgkmcnt(0)\n\ts_barrier" ::: "memory");
  }

  // ---- epilogue: logits + log_softmax; wave w handles local batch w ----
  {
    const ushort_t* hrow = &hB[0][w * HPAD + (lane << 2)];
    float h0 = bf2f(hrow[0]), h1 = bf2f(hrow[1]), h2 = bf2f(hrow[2]), h3 = bf2f(hrow[3]);
    float d[3];
#pragma unroll
    for (int o = 0; o < 3; ++o) {
      size_t base = (size_t)o * H_ + (lane << 2);
      d[o] = ldf(W_out, base, isb) * h0 + ldf(W_out, base + 1, isb) * h1 +
             ldf(W_out, base + 2, isb) * h2 + ldf(W_out, base + 3, isb) * h3;
      for (int off = 1; off < 64; off <<= 1) d[o] += __shfl_xor(d[o], off);
    }
    if (lane == 0) {
      float l0 = d[0] + ldf(b_out, 0, isb);
      float l1 = d[1] + ldf(b_out, 1, isb);
      float l2 = d[2] + ldf(b_out, 2, isb);
      float m = fmaxf(l0, fmaxf(l1, l2));
      float s = __builtin_amdgcn_exp2f((l0 - m) * 1.442695041f) +
                __builtin_amdgcn_exp2f((l1 - m) * 1.442695041f) +
                __builtin_amdgcn_exp2f((l2 - m) * 1.442695041f);
      float ls = __builtin_amdgcn_logf(s) * 0.6931471806f;
      size_t ob = (size_t)(wg * 16 + w) * 3;
      float o0 = l0 - m - ls, o1 = l1 - m - ls, o2 = l2 - m - ls;
      if (isb) {
        ushort_t* ob16 = (ushort_t*)out;
        ob16[ob] = f2bf(o0); ob16[ob + 1] = f2bf(o1); ob16[ob + 2] = f2bf(o2);
      } else {
        float* of = (float*)out;
        of[ob] = o0; of[ob + 1] = o1; of[ob + 2] = o2;
      }
    }
  }
  // ---- h_final copy, coalesced ----
  {
    int e = tid << 2;
    int bb = e >> 8, uu = e & 255;
    const ushort_t* src = &hB[0][bb * HPAD + uu];
    size_t oi = 12288 + (size_t)wg * 4096 + e;
    if (isb) {
      *(uint2*)((ushort_t*)out + oi) = *(const uint2*)src;
    } else {
      float* of = (float*)out;
      of[oi] = bf2f(src[0]); of[oi + 1] = bf2f(src[1]);
      of[oi + 2] = bf2f(src[2]); of[oi + 3] = bf2f(src[3]);
    }
  }
}

extern "C" void kernel_launch(void* const* d_in, const int* in_sizes, int n_in,
                              void* d_out, int out_size, void* d_ws, size_t ws_size,
                              hipStream_t stream) {
  (void)in_sizes; (void)n_in; (void)out_size; (void)d_ws; (void)ws_size;
  const int* input = (const int*)d_in[0];
  const void* hidden = d_in[1];
  const void* embed  = d_in[2];
  const void* W_ih   = d_in[3];
  const void* W_hh   = d_in[4];
  const void* b_ih   = d_in[5];
  const void* b_hh   = d_in[6];
  const void* W_out  = d_in[7];
  const void* b_out  = d_in[8];

  prep<<<345, 256, 0, stream>>>(W_hh, embed, W_ih, b_ih, b_hh);
  gru_persist<<<B_ / 16, 1024, 0, stream>>>(input, hidden, b_hh, W_out, b_out,
                                            (const ushort_t*)embed, d_out);
}